// Round 9
// baseline (460.126 us; speedup 1.0000x reference)
//
#include <hip/hip_runtime.h>
#include <hip/hip_bf16.h>
#include <math.h>

#define NNODES 50000
#define NEDGES 800000
#define HF 256
#define NEG_SLOPE 0.2f
#define NB 196        // ceil(NNODES/256)
#define APAD 12288    // 48 pad rows * 256 for async over-read

typedef short bf16x8 __attribute__((ext_vector_type(8)));
typedef float f32x4 __attribute__((ext_vector_type(4)));
typedef float f32x2 __attribute__((ext_vector_type(2)));

__device__ __forceinline__ unsigned short f2bf(float f) {
  unsigned u = __float_as_uint(f);
  unsigned r = u + 0x7FFFu + ((u >> 16) & 1u);
  return (unsigned short)(r >> 16);
}
__device__ __forceinline__ float bf2f(unsigned short u) {
  return __uint_as_float((unsigned)u << 16);
}
__device__ __forceinline__ uint2 pack4(const float* v) {
  uint2 r;
  r.x = (unsigned)f2bf(v[0]) | ((unsigned)f2bf(v[1]) << 16);
  r.y = (unsigned)f2bf(v[2]) | ((unsigned)f2bf(v[3]) << 16);
  return r;
}
__device__ __forceinline__ uint4 pack8(const float* v) {
  uint4 r;
  r.x = (unsigned)f2bf(v[0]) | ((unsigned)f2bf(v[1]) << 16);
  r.y = (unsigned)f2bf(v[2]) | ((unsigned)f2bf(v[3]) << 16);
  r.z = (unsigned)f2bf(v[4]) | ((unsigned)f2bf(v[5]) << 16);
  r.w = (unsigned)f2bf(v[6]) | ((unsigned)f2bf(v[7]) << 16);
  return r;
}

// storage-position -> true column (within-row permutation, blocks of 64):
// p = fr*4 + j + 64*w  <->  c = j*16 + fr + 64*w
__device__ __forceinline__ int permc(int p) {
  return (p & 192) | ((p & 3) << 4) | ((p & 63) >> 2);
}

// async 16B global->LDS (wave-uniform LDS base + lane*16)
#define GLOAD_LDS16(gsrc, ldst)                                                \
  __builtin_amdgcn_global_load_lds(                                           \
      (const __attribute__((address_space(1))) unsigned int*)(const void*)(gsrc), \
      (__attribute__((address_space(3))) unsigned int*)(void*)(ldst), 16, 0, 0)

// inverse of slot = (row*4 + kb) ^ (row&7)  [16B granules of a Rx(32 bf16) tile]
__device__ __forceinline__ void slot_decode(int s, int& row, int& kb) {
  row = ((s >> 3) << 1) | (((s >> 2) & 1) ^ ((s >> 4) & 1));
  kb  = ((s & 1) ^ (row & 1)) | ((((s >> 1) & 1) ^ ((s >> 3) & 1)) << 1);
}

// ---------------- hv fp32 -> bf16 (once; raw feature order) -----------------
__global__ __launch_bounds__(256)
void conv_hv(const float* __restrict__ x, unsigned short* __restrict__ o) {
  size_t i = (size_t)(blockIdx.x * 256 + threadIdx.x) * 8;
  float4 a = *(const float4*)(x + i);
  float4 b = *(const float4*)(x + i + 4);
  float v[8] = {a.x, a.y, a.z, a.w, b.x, b.y, b.z, b.w};
  *(uint4*)(o + i) = pack8(v);
}

// ---------------- W^T bf16 pre-convert ---------------------------------------
// mat 0 (W_in): WT[n][k] = W[k][n] (A = raw hv).
// mats 1-3 (fc): WT[n][p] = W[permc(p)][n] (A = permuted hrelu).
__global__ __launch_bounds__(256)
void conv_wt(const float* __restrict__ W0, const float* __restrict__ W1,
             const float* __restrict__ W2, const float* __restrict__ W3,
             unsigned short* __restrict__ WT) {
  int mat = blockIdx.y;
  const float* W = mat == 0 ? W0 : (mat == 1 ? W1 : (mat == 2 ? W2 : W3));
  int i = blockIdx.x * 256 + threadIdx.x;
  int n = i >> 8, p = i & 255;
  int k = (mat == 0) ? p : permc(p);
  WT[(size_t)mat * 65536 + i] = f2bf(W[(size_t)k * 256 + n]);
}

// ---------------- bf16 MFMA GEMM, BM=64 BN=256 BK=32, async dbuf ------------
// BIAS_RELU variant: C = bf16 hrelu (permuted cols), +bias +relu.
// DOTS variant:      C = fp8-e4m3 feat (permuted cols), + fused el/er dots.
template<bool BIAS_RELU, bool DOTS>
__global__ __launch_bounds__(256)
void gemm_bf16(const unsigned short* __restrict__ A, const unsigned short* __restrict__ WT,
               const float* __restrict__ bias,
               const float* __restrict__ al, const float* __restrict__ ar,
               void* __restrict__ Cv,
               float* __restrict__ el, float* __restrict__ er, int M) {
  __shared__ unsigned short As[2][64 * 32];    // 8 KB
  __shared__ unsigned short Bs[2][256 * 32];   // 32 KB
  __shared__ float sEl[64][4], sEr[64][4];     // 2 KB (DOTS combine)
  const int t = threadIdx.x;
  const int lane = t & 63;
  const int w = t >> 6;               // 0..3
  const int wc = w * 64;              // col quarter
  const int brow = blockIdx.x * 64;

  f32x4 acc[4][4];
#pragma unroll
  for (int i = 0; i < 4; i++)
#pragma unroll
    for (int j = 0; j < 4; j++) acc[i][j] = (f32x4)(0.f);

  // staging: A 256 granules (wave w: slots w*64+lane); B 1024 (4 per lane)
  int rA, kA;
  slot_decode(w * 64 + lane, rA, kA);
  const unsigned short* aP = A + (size_t)(brow + rA) * 256 + kA * 8;
  const unsigned short* bP[4];
#pragma unroll
  for (int i = 0; i < 4; i++) {
    int rB, kB;
    slot_decode(w * 256 + i * 64 + lane, rB, kB);
    bP[i] = WT + (size_t)rB * 256 + kB * 8;
  }
  unsigned short* lA[2] = {&As[0][w * 512], &As[1][w * 512]};
  unsigned short* lB[2] = {&Bs[0][w * 2048], &Bs[1][w * 2048]};

#define STAGE(buf, kt)                                                         \
  do {                                                                         \
    GLOAD_LDS16(aP + (kt) * 32, lA[buf]);                                      \
    GLOAD_LDS16(bP[0] + (kt) * 32, lB[buf]);                                   \
    GLOAD_LDS16(bP[1] + (kt) * 32, lB[buf] + 512);                             \
    GLOAD_LDS16(bP[2] + (kt) * 32, lB[buf] + 1024);                            \
    GLOAD_LDS16(bP[3] + (kt) * 32, lB[buf] + 1536);                            \
  } while (0)

  // fragment read offsets (swizzled byte offsets within one buffer)
  const int fr = lane & 15, fq = lane >> 4;
  int ard[4], brd[4];
#pragma unroll
  for (int i = 0; i < 4; i++) {
    int rowA = i * 16 + fr;
    ard[i] = ((rowA * 64 + fq * 16) ^ ((rowA & 7) << 4));
    int rowB = wc + i * 16 + fr;
    brd[i] = ((rowB * 64 + fq * 16) ^ ((rowB & 7) << 4));
  }

  STAGE(0, 0);
  __syncthreads();   // vmcnt(0) drain + barrier: buf0 ready
  int cur = 0;
#pragma unroll
  for (int kt = 0; kt < 8; kt++) {
    if (kt < 7) STAGE(cur ^ 1, kt + 1);   // next tile hides under MFMA
    bf16x8 af[4], bfr[4];
#pragma unroll
    for (int i = 0; i < 4; i++) {
      af[i]  = *(const bf16x8*)((const char*)As[cur] + ard[i]);
      bfr[i] = *(const bf16x8*)((const char*)Bs[cur] + brd[i]);
    }
#pragma unroll
    for (int i = 0; i < 4; i++)
#pragma unroll
      for (int j = 0; j < 4; j++)
        acc[i][j] = __builtin_amdgcn_mfma_f32_16x16x32_bf16(af[i], bfr[j], acc[i][j], 0, 0, 0);
    if (kt < 7) {
      __syncthreads();
      cur ^= 1;
    }
  }
#undef STAGE

  // epilogue: D row = (lane>>4)*4 + reg, col = wc + j*16 + fr.
  // Store positions p = wc + fr*4 + j (permuted layout): j-values contiguous.
#pragma unroll
  for (int i = 0; i < 4; i++) {
#pragma unroll
    for (int r = 0; r < 4; r++) {
      int row = brow + i * 16 + fq * 4 + r;
      if (row < M) {
        float v[4];
#pragma unroll
        for (int j = 0; j < 4; j++) {
          float x = acc[i][j][r];
          if (BIAS_RELU) x = fmaxf(x + bias[wc + j * 16 + fr], 0.f);
          v[j] = x;
        }
        if constexpr (DOTS) {   // fp8 e4m3 out (4 bytes)
          int pk = __builtin_amdgcn_cvt_pk_fp8_f32(v[0], v[1], 0, false);
          pk = __builtin_amdgcn_cvt_pk_fp8_f32(v[2], v[3], pk, true);
          *(unsigned*)((unsigned char*)Cv + (size_t)row * 256 + wc + fr * 4) = (unsigned)pk;
        } else {                // bf16 out (8 bytes)
          *(uint2*)((unsigned short*)Cv + (size_t)row * 256 + wc + fr * 4) = pack4(v);
        }
      }
    }
  }

  if constexpr (DOTS) {
    // el/er from fp32 acc (exact): j-sum -> fr-lane reduce -> LDS combine.
    float alv[4], arv[4];
#pragma unroll
    for (int j = 0; j < 4; j++) {
      int colj = wc + j * 16 + fr;
      alv[j] = al[colj];
      arv[j] = ar[colj];
    }
    float pel[16], per_[16];
#pragma unroll
    for (int i = 0; i < 4; i++)
#pragma unroll
      for (int r = 0; r < 4; r++) {
        float se = 0.f, sr = 0.f;
#pragma unroll
        for (int j = 0; j < 4; j++) {
          se = fmaf(acc[i][j][r], alv[j], se);
          sr = fmaf(acc[i][j][r], arv[j], sr);
        }
        pel[i * 4 + r] = se;
        per_[i * 4 + r] = sr;
      }
#pragma unroll
    for (int off = 1; off < 16; off <<= 1)
#pragma unroll
      for (int k = 0; k < 16; k++) {
        pel[k] += __shfl_xor(pel[k], off);
        per_[k] += __shfl_xor(per_[k], off);
      }
    if (fr == 0) {
#pragma unroll
      for (int i = 0; i < 4; i++)
#pragma unroll
        for (int r = 0; r < 4; r++) {
          int rl = i * 16 + fq * 4 + r;
          sEl[rl][w] = pel[i * 4 + r];
          sEr[rl][w] = per_[i * 4 + r];
        }
    }
    __syncthreads();
    if (t < 64) {
      int row = brow + t;
      if (row < M) {
        el[row] = sEl[t][0] + sEl[t][1] + sEl[t][2] + sEl[t][3];
        er[row] = sEr[t][0] + sEr[t][1] + sEr[t][2] + sEr[t][3];
      }
    }
  }
}

// ---------------- CSR build -------------------------------------------------
__global__ __launch_bounds__(256)
void hist_dst(const int* __restrict__ dst, int* __restrict__ cnt) {
  int e = blockIdx.x * 256 + threadIdx.x;
  if (e < NEDGES) atomicAdd(&cnt[dst[e]], 1);
}

__global__ __launch_bounds__(256)
void block_sums(const int* __restrict__ cnt, int* __restrict__ bsum) {
  __shared__ int sm[256];
  int t = threadIdx.x;
  int i = blockIdx.x * 256 + t;
  sm[t] = (i < NNODES) ? cnt[i] : 0;
  __syncthreads();
  for (int off = 128; off; off >>= 1) {
    if (t < off) sm[t] += sm[t + off];
    __syncthreads();
  }
  if (t == 0) bsum[blockIdx.x] = sm[0];
}

__global__ __launch_bounds__(256)
void scan_bsums(const int* __restrict__ bsum, int* __restrict__ boff) {
  __shared__ int sm[256];
  int t = threadIdx.x;
  sm[t] = (t < NB) ? bsum[t] : 0;
  __syncthreads();
  for (int off = 1; off < 256; off <<= 1) {
    int v = (t >= off) ? sm[t - off] : 0;
    __syncthreads();
    sm[t] += v;
    __syncthreads();
  }
  if (t < NB) boff[t] = (t == 0) ? 0 : sm[t - 1];
}

__global__ __launch_bounds__(256)
void write_rowptr(const int* __restrict__ cnt, const int* __restrict__ boff,
                  int* __restrict__ rowptr, int* __restrict__ woff) {
  __shared__ int sm[256];
  int t = threadIdx.x;
  int i = blockIdx.x * 256 + t;
  int v = (i < NNODES) ? cnt[i] : 0;
  sm[t] = v;
  __syncthreads();
  for (int off = 1; off < 256; off <<= 1) {
    int x = (t >= off) ? sm[t - off] : 0;
    __syncthreads();
    sm[t] += x;
    __syncthreads();
  }
  int excl = boff[blockIdx.x] + sm[t] - v;
  if (i < NNODES) { rowptr[i] = excl; woff[i] = excl; }
  if (i == NNODES - 1) rowptr[NNODES] = excl + v;
}

__global__ __launch_bounds__(256)
void scatter_csr(const int* __restrict__ src, const int* __restrict__ dst,
                 int* __restrict__ woff, int* __restrict__ col) {
  int e = blockIdx.x * 256 + threadIdx.x;
  if (e >= NEDGES) return;
  int d = dst[e];
  int p = atomicAdd(&woff[d], 1);
  col[p] = src[e];
}

// ---------------- fused GAT edge phase: fp8 gather, whole-wave row ----------
// One wave per dst; lane owns 4 permuted positions (4 B fp8 per edge).
// Edge (s, ex) broadcast via readlane; HW fp8->f32 converts; packed fma.
template<bool WRITE_RELU>
__global__ __launch_bounds__(256)
void gat_csr(const int* __restrict__ rowptr, const int* __restrict__ col,
             const float* __restrict__ el, const float* __restrict__ er,
             const unsigned char* __restrict__ feat8, const float* __restrict__ bias,
             unsigned short* __restrict__ h, unsigned short* __restrict__ hrelu) {
  int d = blockIdx.x * 4 + (threadIdx.x >> 6);
  int lane = threadIdx.x & 63;
  if (d >= NNODES) return;
  const int start = rowptr[d], end = rowptr[d + 1];
  // permuted bias: position p = 4*lane+m -> col (lane>>4)*64 + m*16 + (lane&15)
  float bv[4];
#pragma unroll
  for (int m = 0; m < 4; m++)
    bv[m] = bias[((lane >> 4) << 6) | (m << 4) | (lane & 15)];
  const size_t obase = (size_t)d * HF + lane * 4;
  if (start == end) {
    *(uint2*)(h + obase) = pack4(bv);
    if (WRITE_RELU) {
      float rv[4] = {fmaxf(bv[0], 0.f), fmaxf(bv[1], 0.f), fmaxf(bv[2], 0.f), fmaxf(bv[3], 0.f)};
      *(uint2*)(hrelu + obase) = pack4(rv);
    }
    return;
  }
  const float erd = er[d];

  float sm = 0.f;
  f32x2 acl = (f32x2)(0.f), ach = (f32x2)(0.f);

  for (int c0 = start; c0 < end; c0 += 64) {
    int j = c0 + lane;
    float ex = 0.f;
    int s = 0;
    if (j < end) {
      s = col[j];
      float x = el[s] + erd;
      x = x > 0.f ? x : NEG_SLOPE * x;
      ex = __expf(x);
    }
    sm += ex;
    int n = min(64, end - c0);
    for (int q = 0; q < n; q += 8) {
      int su[8];
      float eu[8];
#pragma unroll
      for (int u = 0; u < 8; u++) {
        su[u] = __builtin_amdgcn_readlane(s, q + u);
        eu[u] = __uint_as_float(
            (unsigned)__builtin_amdgcn_readlane((int)__float_as_uint(ex), q + u));
      }
      unsigned fv[8];
#pragma unroll
      for (int u = 0; u < 8; u++)
        fv[u] = *(const unsigned*)(feat8 + (size_t)su[u] * 256 + lane * 4);
#pragma unroll
      for (int u = 0; u < 8; u++) {
        f32x2 lo = __builtin_amdgcn_cvt_pk_f32_fp8((int)fv[u], false);
        f32x2 hi = __builtin_amdgcn_cvt_pk_f32_fp8((int)fv[u], true);
        f32x2 ev = {eu[u], eu[u]};
        acl = lo * ev + acl;
        ach = hi * ev + ach;
      }
    }
  }
#pragma unroll
  for (int off = 32; off; off >>= 1) sm += __shfl_xor(sm, off);

  const float rcp = 1.f / sm;
  float ov[4];
  ov[0] = fmaf(acl.x, rcp, bv[0]);
  ov[1] = fmaf(acl.y, rcp, bv[1]);
  ov[2] = fmaf(ach.x, rcp, bv[2]);
  ov[3] = fmaf(ach.y, rcp, bv[3]);
  *(uint2*)(h + obase) = pack4(ov);
  if (WRITE_RELU) {
    float rv[4] = {fmaxf(ov[0], 0.f), fmaxf(ov[1], 0.f), fmaxf(ov[2], 0.f), fmaxf(ov[3], 0.f)};
    *(uint2*)(hrelu + obase) = pack4(rv);
  }
}

// ---------------- readout: sigmoid(concat(h1,h2,h3) @ Wro + bro) ------------
// h stored with permuted cols: position q -> true col permc(q).
__global__ __launch_bounds__(256)
void readout(const unsigned short* __restrict__ h1, const unsigned short* __restrict__ h2,
             const unsigned short* __restrict__ h3, const float* __restrict__ Wro,
             const float* __restrict__ bro, float* __restrict__ out) {
  int row = blockIdx.x * 4 + (threadIdx.x >> 6);
  int lane = threadIdx.x & 63;
  if (row >= NNODES) return;
  float acc[8];
#pragma unroll
  for (int t2 = 0; t2 < 8; t2++) acc[t2] = 0.f;
  const unsigned short* hs[3] = {h1 + (size_t)row * HF, h2 + (size_t)row * HF,
                                 h3 + (size_t)row * HF};
#pragma unroll
  for (int part = 0; part < 3; ++part) {
    const unsigned short* hp = hs[part];
#pragma unroll
    for (int kk = 0; kk < HF; kk += 64) {
      int q = kk + lane;
      float x = bf2f(hp[q]);
      const float* w = Wro + (size_t)(part * HF + permc(q)) * 8;
#pragma unroll
      for (int t2 = 0; t2 < 8; t2++) acc[t2] = fmaf(x, w[t2], acc[t2]);
    }
  }
#pragma unroll
  for (int t2 = 0; t2 < 8; t2++)
#pragma unroll
    for (int off = 32; off; off >>= 1) acc[t2] += __shfl_xor(acc[t2], off);
  if (lane == 0) {
#pragma unroll
    for (int t2 = 0; t2 < 8; t2++) {
      float v = acc[t2] + bro[t2];
      out[(size_t)row * 8 + t2] = 1.f / (1.f + expf(-v));
    }
  }
}

extern "C" void kernel_launch(void* const* d_in, const int* in_sizes, int n_in,
                              void* d_out, int out_size, void* d_ws, size_t ws_size,
                              hipStream_t stream) {
  const float* hv   = (const float*)d_in[0];
  const int*   src  = (const int*)d_in[1];
  const int*   dst  = (const int*)d_in[2];
  const float* W_in = (const float*)d_in[3];
  const float* b_in = (const float*)d_in[4];
  const float* W_ro = (const float*)d_in[5];
  const float* b_ro = (const float*)d_in[6];
  const float* fc[3]   = {(const float*)d_in[7],  (const float*)d_in[11], (const float*)d_in[15]};
  const float* al[3]   = {(const float*)d_in[8],  (const float*)d_in[12], (const float*)d_in[16]};
  const float* ar[3]   = {(const float*)d_in[9],  (const float*)d_in[13], (const float*)d_in[17]};
  const float* bias[3] = {(const float*)d_in[10], (const float*)d_in[14], (const float*)d_in[18]};
  float* out = (float*)d_out;

  const size_t NH = (size_t)NNODES * HF;   // 12.8M elems
  unsigned short* h1    = (unsigned short*)d_ws;
  unsigned short* h2    = h1 + NH;
  unsigned short* h3    = h2 + NH;
  unsigned char*  feat8 = (unsigned char*)(h3 + NH);   // NH bytes (fp8)
  unsigned short* hrelu = (unsigned short*)(feat8 + NH);   // +APAD over-read
  unsigned short* hvbf  = hrelu + NH + APAD;               // +APAD over-read
  float* el   = (float*)(hvbf + NH + APAD);
  float* er   = el + NNODES;
  int* rowptr = (int*)(er + NNODES);          // NNODES+1
  int* woff   = rowptr + NNODES + 1;          // NNODES
  int* cnt    = woff + NNODES;                // NNODES
  int* bsum   = cnt + NNODES;                 // 256
  int* boff   = bsum + 256;                   // 256
  int* col    = boff + 256;                   // NEDGES
  unsigned short* WT = (unsigned short*)(col + NEDGES);  // 4*65536 bf16

  const int gemm_grid = (NNODES + 63) / 64;     // 782, BM=64, all cols
  const int rd_grid = (NNODES + 3) / 4;
  const int ep_grid = (NEDGES + 255) / 256;
  const int gat_grid = (NNODES + 3) / 4;

  // ---- one-time converts ----
  conv_hv<<<(int)(NH / 2048), 256, 0, stream>>>(hv, hvbf);
  conv_wt<<<dim3(256, 4), 256, 0, stream>>>(W_in, fc[0], fc[1], fc[2], WT);

  // ---- build CSR (dst-sorted adjacency), reused by all 3 layers ----
  hipMemsetAsync(cnt, 0, NNODES * sizeof(int), stream);
  hist_dst<<<ep_grid, 256, 0, stream>>>(dst, cnt);
  block_sums<<<NB, 256, 0, stream>>>(cnt, bsum);
  scan_bsums<<<1, 256, 0, stream>>>(bsum, boff);
  write_rowptr<<<NB, 256, 0, stream>>>(cnt, boff, rowptr, woff);
  scatter_csr<<<ep_grid, 256, 0, stream>>>(src, dst, woff, col);

  // hrelu = relu(hv @ W_in + b_in)   (bf16, permuted cols)
  gemm_bf16<true, false><<<gemm_grid, 256, 0, stream>>>(
      hvbf, WT, b_in, nullptr, nullptr, hrelu, nullptr, nullptr, NNODES);

  unsigned short* houts[3] = {h1, h2, h3};
  for (int l = 0; l < 3; ++l) {
    unsigned short* hl = houts[l];
    // feat8 = fp8(relu(h_prev) @ fc_l), fused exact el/er dots
    gemm_bf16<false, true><<<gemm_grid, 256, 0, stream>>>(
        hrelu, WT + (size_t)(l + 1) * 65536, nullptr, al[l], ar[l], feat8, el, er, NNODES);
    if (l < 2)
      gat_csr<true><<<gat_grid, 256, 0, stream>>>(rowptr, col, el, er, feat8, bias[l], hl, hrelu);
    else
      gat_csr<false><<<gat_grid, 256, 0, stream>>>(rowptr, col, el, er, feat8, bias[l], hl, hrelu);
  }

  readout<<<rd_grid, 256, 0, stream>>>(h1, h2, h3, W_ro, b_ro, out);
}

// Round 10
// 384.416 us; speedup vs baseline: 1.1969x; 1.1969x over previous
//
#include <hip/hip_runtime.h>
#include <hip/hip_bf16.h>
#include <math.h>

#define NNODES 50000
#define NEDGES 800000
#define HF 256
#define NEG_SLOPE 0.2f
#define NB 196        // ceil(NNODES/256)
#define APAD 12288    // 48 pad rows * 256 for async over-read

typedef short bf16x8 __attribute__((ext_vector_type(8)));
typedef float f32x4 __attribute__((ext_vector_type(4)));
typedef float f32x2 __attribute__((ext_vector_type(2)));

__device__ __forceinline__ unsigned short f2bf(float f) {
  unsigned u = __float_as_uint(f);
  unsigned r = u + 0x7FFFu + ((u >> 16) & 1u);
  return (unsigned short)(r >> 16);
}
__device__ __forceinline__ float bf2f(unsigned short u) {
  return __uint_as_float((unsigned)u << 16);
}
__device__ __forceinline__ uint2 pack4(const float* v) {
  uint2 r;
  r.x = (unsigned)f2bf(v[0]) | ((unsigned)f2bf(v[1]) << 16);
  r.y = (unsigned)f2bf(v[2]) | ((unsigned)f2bf(v[3]) << 16);
  return r;
}
__device__ __forceinline__ uint4 pack8(const float* v) {
  uint4 r;
  r.x = (unsigned)f2bf(v[0]) | ((unsigned)f2bf(v[1]) << 16);
  r.y = (unsigned)f2bf(v[2]) | ((unsigned)f2bf(v[3]) << 16);
  r.z = (unsigned)f2bf(v[4]) | ((unsigned)f2bf(v[5]) << 16);
  r.w = (unsigned)f2bf(v[6]) | ((unsigned)f2bf(v[7]) << 16);
  return r;
}

// storage-position -> true column (within-row permutation, blocks of 64):
// p = fr*4 + j + 64*w  <->  c = j*16 + fr + 64*w
__device__ __forceinline__ int permc(int p) {
  return (p & 192) | ((p & 3) << 4) | ((p & 63) >> 2);
}

// async 16B global->LDS (wave-uniform LDS base + lane*16)
#define GLOAD_LDS16(gsrc, ldst)                                                \
  __builtin_amdgcn_global_load_lds(                                           \
      (const __attribute__((address_space(1))) unsigned int*)(const void*)(gsrc), \
      (__attribute__((address_space(3))) unsigned int*)(void*)(ldst), 16, 0, 0)

// inverse of slot = (row*4 + kb) ^ (row&7)  [16B granules of a Rx(32 bf16) tile]
__device__ __forceinline__ void slot_decode(int s, int& row, int& kb) {
  row = ((s >> 3) << 1) | (((s >> 2) & 1) ^ ((s >> 4) & 1));
  kb  = ((s & 1) ^ (row & 1)) | ((((s >> 1) & 1) ^ ((s >> 3) & 1)) << 1);
}

// ---------------- hv fp32 -> bf16 (once; raw feature order) -----------------
__global__ __launch_bounds__(256)
void conv_hv(const float* __restrict__ x, unsigned short* __restrict__ o) {
  size_t i = (size_t)(blockIdx.x * 256 + threadIdx.x) * 8;
  float4 a = *(const float4*)(x + i);
  float4 b = *(const float4*)(x + i + 4);
  float v[8] = {a.x, a.y, a.z, a.w, b.x, b.y, b.z, b.w};
  *(uint4*)(o + i) = pack8(v);
}

// ---------------- W^T bf16 pre-convert ---------------------------------------
// mat 0 (W_in): WT[n][k] = W[k][n] (A = raw hv).
// mats 1-3 (fc): WT[n][p] = W[permc(p)][n] (A = permuted hrelu).
__global__ __launch_bounds__(256)
void conv_wt(const float* __restrict__ W0, const float* __restrict__ W1,
             const float* __restrict__ W2, const float* __restrict__ W3,
             unsigned short* __restrict__ WT) {
  int mat = blockIdx.y;
  const float* W = mat == 0 ? W0 : (mat == 1 ? W1 : (mat == 2 ? W2 : W3));
  int i = blockIdx.x * 256 + threadIdx.x;
  int n = i >> 8, p = i & 255;
  int k = (mat == 0) ? p : permc(p);
  WT[(size_t)mat * 65536 + i] = f2bf(W[(size_t)k * 256 + n]);
}

// ---------------- Wro permuted copy (once): Wro_p[part*256+q] = Wro[part*256+permc(q)]
__global__ __launch_bounds__(256)
void conv_wro(const float* __restrict__ Wro, float* __restrict__ Wro_p) {
  int i = blockIdx.x * 256 + threadIdx.x;   // 0..6143
  int row = i >> 3, t = i & 7;
  int part = row >> 8, q = row & 255;
  Wro_p[i] = Wro[(size_t)((part << 8) + permc(q)) * 8 + t];
}

// ---------------- bf16 MFMA GEMM, BM=64 BN=256 BK=32, async dbuf ------------
// BIAS_RELU variant: C = bf16 hrelu (permuted cols), +bias +relu.
// DOTS variant:      C = fp8-e4m3 feat (permuted cols), + fused el/er dots.
template<bool BIAS_RELU, bool DOTS>
__global__ __launch_bounds__(256)
void gemm_bf16(const unsigned short* __restrict__ A, const unsigned short* __restrict__ WT,
               const float* __restrict__ bias,
               const float* __restrict__ al, const float* __restrict__ ar,
               void* __restrict__ Cv,
               float* __restrict__ el, float* __restrict__ er, int M) {
  __shared__ unsigned short As[2][64 * 32];    // 8 KB
  __shared__ unsigned short Bs[2][256 * 32];   // 32 KB
  __shared__ float sEl[64][4], sEr[64][4];     // 2 KB (DOTS combine)
  const int t = threadIdx.x;
  const int lane = t & 63;
  const int w = t >> 6;               // 0..3
  const int wc = w * 64;              // col quarter
  const int brow = blockIdx.x * 64;

  f32x4 acc[4][4];
#pragma unroll
  for (int i = 0; i < 4; i++)
#pragma unroll
    for (int j = 0; j < 4; j++) acc[i][j] = (f32x4)(0.f);

  // staging: A 256 granules (wave w: slots w*64+lane); B 1024 (4 per lane)
  int rA, kA;
  slot_decode(w * 64 + lane, rA, kA);
  const unsigned short* aP = A + (size_t)(brow + rA) * 256 + kA * 8;
  const unsigned short* bP[4];
#pragma unroll
  for (int i = 0; i < 4; i++) {
    int rB, kB;
    slot_decode(w * 256 + i * 64 + lane, rB, kB);
    bP[i] = WT + (size_t)rB * 256 + kB * 8;
  }
  unsigned short* lA[2] = {&As[0][w * 512], &As[1][w * 512]};
  unsigned short* lB[2] = {&Bs[0][w * 2048], &Bs[1][w * 2048]};

#define STAGE(buf, kt)                                                         \
  do {                                                                         \
    GLOAD_LDS16(aP + (kt) * 32, lA[buf]);                                      \
    GLOAD_LDS16(bP[0] + (kt) * 32, lB[buf]);                                   \
    GLOAD_LDS16(bP[1] + (kt) * 32, lB[buf] + 512);                             \
    GLOAD_LDS16(bP[2] + (kt) * 32, lB[buf] + 1024);                            \
    GLOAD_LDS16(bP[3] + (kt) * 32, lB[buf] + 1536);                            \
  } while (0)

  // fragment read offsets (swizzled byte offsets within one buffer)
  const int fr = lane & 15, fq = lane >> 4;
  int ard[4], brd[4];
#pragma unroll
  for (int i = 0; i < 4; i++) {
    int rowA = i * 16 + fr;
    ard[i] = ((rowA * 64 + fq * 16) ^ ((rowA & 7) << 4));
    int rowB = wc + i * 16 + fr;
    brd[i] = ((rowB * 64 + fq * 16) ^ ((rowB & 7) << 4));
  }

  STAGE(0, 0);
  __syncthreads();   // vmcnt(0) drain + barrier: buf0 ready
  int cur = 0;
#pragma unroll
  for (int kt = 0; kt < 8; kt++) {
    if (kt < 7) STAGE(cur ^ 1, kt + 1);   // next tile hides under MFMA
    bf16x8 af[4], bfr[4];
#pragma unroll
    for (int i = 0; i < 4; i++) {
      af[i]  = *(const bf16x8*)((const char*)As[cur] + ard[i]);
      bfr[i] = *(const bf16x8*)((const char*)Bs[cur] + brd[i]);
    }
#pragma unroll
    for (int i = 0; i < 4; i++)
#pragma unroll
      for (int j = 0; j < 4; j++)
        acc[i][j] = __builtin_amdgcn_mfma_f32_16x16x32_bf16(af[i], bfr[j], acc[i][j], 0, 0, 0);
    if (kt < 7) {
      __syncthreads();
      cur ^= 1;
    }
  }
#undef STAGE

  // epilogue: D row = (lane>>4)*4 + reg, col = wc + j*16 + fr.
  // Store positions p = wc + fr*4 + j (permuted layout): j-values contiguous.
#pragma unroll
  for (int i = 0; i < 4; i++) {
#pragma unroll
    for (int r = 0; r < 4; r++) {
      int row = brow + i * 16 + fq * 4 + r;
      if (row < M) {
        float v[4];
#pragma unroll
        for (int j = 0; j < 4; j++) {
          float x = acc[i][j][r];
          if (BIAS_RELU) x = fmaxf(x + bias[wc + j * 16 + fr], 0.f);
          v[j] = x;
        }
        if constexpr (DOTS) {   // fp8 e4m3 out (4 bytes)
          int pk = __builtin_amdgcn_cvt_pk_fp8_f32(v[0], v[1], 0, false);
          pk = __builtin_amdgcn_cvt_pk_fp8_f32(v[2], v[3], pk, true);
          *(unsigned*)((unsigned char*)Cv + (size_t)row * 256 + wc + fr * 4) = (unsigned)pk;
        } else {                // bf16 out (8 bytes)
          *(uint2*)((unsigned short*)Cv + (size_t)row * 256 + wc + fr * 4) = pack4(v);
        }
      }
    }
  }

  if constexpr (DOTS) {
    // el/er from fp32 acc (exact): j-sum -> fr-lane reduce -> LDS combine.
    float alv[4], arv[4];
#pragma unroll
    for (int j = 0; j < 4; j++) {
      int colj = wc + j * 16 + fr;
      alv[j] = al[colj];
      arv[j] = ar[colj];
    }
    float pel[16], per_[16];
#pragma unroll
    for (int i = 0; i < 4; i++)
#pragma unroll
      for (int r = 0; r < 4; r++) {
        float se = 0.f, sr = 0.f;
#pragma unroll
        for (int j = 0; j < 4; j++) {
          se = fmaf(acc[i][j][r], alv[j], se);
          sr = fmaf(acc[i][j][r], arv[j], sr);
        }
        pel[i * 4 + r] = se;
        per_[i * 4 + r] = sr;
      }
#pragma unroll
    for (int off = 1; off < 16; off <<= 1)
#pragma unroll
      for (int k = 0; k < 16; k++) {
        pel[k] += __shfl_xor(pel[k], off);
        per_[k] += __shfl_xor(per_[k], off);
      }
    if (fr == 0) {
#pragma unroll
      for (int i = 0; i < 4; i++)
#pragma unroll
        for (int r = 0; r < 4; r++) {
          int rl = i * 16 + fq * 4 + r;
          sEl[rl][w] = pel[i * 4 + r];
          sEr[rl][w] = per_[i * 4 + r];
        }
    }
    __syncthreads();
    if (t < 64) {
      int row = brow + t;
      if (row < M) {
        el[row] = sEl[t][0] + sEl[t][1] + sEl[t][2] + sEl[t][3];
        er[row] = sEr[t][0] + sEr[t][1] + sEr[t][2] + sEr[t][3];
      }
    }
  }
}

// ---------------- CSR build -------------------------------------------------
__global__ __launch_bounds__(256)
void hist_dst(const int* __restrict__ dst, int* __restrict__ cnt) {
  int e = blockIdx.x * 256 + threadIdx.x;
  if (e < NEDGES) atomicAdd(&cnt[dst[e]], 1);
}

__global__ __launch_bounds__(256)
void block_sums(const int* __restrict__ cnt, int* __restrict__ bsum) {
  __shared__ int sm[256];
  int t = threadIdx.x;
  int i = blockIdx.x * 256 + t;
  sm[t] = (i < NNODES) ? cnt[i] : 0;
  __syncthreads();
  for (int off = 128; off; off >>= 1) {
    if (t < off) sm[t] += sm[t + off];
    __syncthreads();
  }
  if (t == 0) bsum[blockIdx.x] = sm[0];
}

__global__ __launch_bounds__(256)
void scan_bsums(const int* __restrict__ bsum, int* __restrict__ boff) {
  __shared__ int sm[256];
  int t = threadIdx.x;
  sm[t] = (t < NB) ? bsum[t] : 0;
  __syncthreads();
  for (int off = 1; off < 256; off <<= 1) {
    int v = (t >= off) ? sm[t - off] : 0;
    __syncthreads();
    sm[t] += v;
    __syncthreads();
  }
  if (t < NB) boff[t] = (t == 0) ? 0 : sm[t - 1];
}

__global__ __launch_bounds__(256)
void write_rowptr(const int* __restrict__ cnt, const int* __restrict__ boff,
                  int* __restrict__ rowptr, int* __restrict__ woff) {
  __shared__ int sm[256];
  int t = threadIdx.x;
  int i = blockIdx.x * 256 + t;
  int v = (i < NNODES) ? cnt[i] : 0;
  sm[t] = v;
  __syncthreads();
  for (int off = 1; off < 256; off <<= 1) {
    int x = (t >= off) ? sm[t - off] : 0;
    __syncthreads();
    sm[t] += x;
    __syncthreads();
  }
  int excl = boff[blockIdx.x] + sm[t] - v;
  if (i < NNODES) { rowptr[i] = excl; woff[i] = excl; }
  if (i == NNODES - 1) rowptr[NNODES] = excl + v;
}

__global__ __launch_bounds__(256)
void scatter_csr(const int* __restrict__ src, const int* __restrict__ dst,
                 int* __restrict__ woff, int* __restrict__ col) {
  int e = blockIdx.x * 256 + threadIdx.x;
  if (e >= NEDGES) return;
  int d = dst[e];
  int p = atomicAdd(&woff[d], 1);
  col[p] = src[e];
}

// ---------------- fused GAT edge phase: fp8 gather, whole-wave row ----------
// One wave per dst; lane owns 4 permuted positions (4 B fp8 per edge).
// Edge (s, ex) broadcast via readlane; HW fp8->f32 converts; packed fma.
template<bool WRITE_RELU>
__global__ __launch_bounds__(256)
void gat_csr(const int* __restrict__ rowptr, const int* __restrict__ col,
             const float* __restrict__ el, const float* __restrict__ er,
             const unsigned char* __restrict__ feat8, const float* __restrict__ bias,
             unsigned short* __restrict__ h, unsigned short* __restrict__ hrelu) {
  int d = blockIdx.x * 4 + (threadIdx.x >> 6);
  int lane = threadIdx.x & 63;
  if (d >= NNODES) return;
  const int start = rowptr[d], end = rowptr[d + 1];
  // permuted bias: position p = 4*lane+m -> col (lane>>4)*64 + m*16 + (lane&15)
  float bv[4];
#pragma unroll
  for (int m = 0; m < 4; m++)
    bv[m] = bias[((lane >> 4) << 6) | (m << 4) | (lane & 15)];
  const size_t obase = (size_t)d * HF + lane * 4;
  if (start == end) {
    *(uint2*)(h + obase) = pack4(bv);
    if (WRITE_RELU) {
      float rv[4] = {fmaxf(bv[0], 0.f), fmaxf(bv[1], 0.f), fmaxf(bv[2], 0.f), fmaxf(bv[3], 0.f)};
      *(uint2*)(hrelu + obase) = pack4(rv);
    }
    return;
  }
  const float erd = er[d];

  float sm = 0.f;
  f32x2 acl = (f32x2)(0.f), ach = (f32x2)(0.f);

  for (int c0 = start; c0 < end; c0 += 64) {
    int j = c0 + lane;
    float ex = 0.f;
    int s = 0;
    if (j < end) {
      s = col[j];
      float x = el[s] + erd;
      x = x > 0.f ? x : NEG_SLOPE * x;
      ex = __expf(x);
    }
    sm += ex;
    int n = min(64, end - c0);
    for (int q = 0; q < n; q += 8) {
      int su[8];
      float eu[8];
#pragma unroll
      for (int u = 0; u < 8; u++) {
        su[u] = __builtin_amdgcn_readlane(s, q + u);
        eu[u] = __uint_as_float(
            (unsigned)__builtin_amdgcn_readlane((int)__float_as_uint(ex), q + u));
      }
      unsigned fv[8];
#pragma unroll
      for (int u = 0; u < 8; u++)
        fv[u] = *(const unsigned*)(feat8 + (size_t)su[u] * 256 + lane * 4);
#pragma unroll
      for (int u = 0; u < 8; u++) {
        f32x2 lo = __builtin_amdgcn_cvt_pk_f32_fp8((int)fv[u], false);
        f32x2 hi = __builtin_amdgcn_cvt_pk_f32_fp8((int)fv[u], true);
        f32x2 ev = {eu[u], eu[u]};
        acl = lo * ev + acl;
        ach = hi * ev + ach;
      }
    }
  }
#pragma unroll
  for (int off = 32; off; off >>= 1) sm += __shfl_xor(sm, off);

  const float rcp = 1.f / sm;
  float ov[4];
  ov[0] = fmaf(acl.x, rcp, bv[0]);
  ov[1] = fmaf(acl.y, rcp, bv[1]);
  ov[2] = fmaf(ach.x, rcp, bv[2]);
  ov[3] = fmaf(ach.y, rcp, bv[3]);
  *(uint2*)(h + obase) = pack4(ov);
  if (WRITE_RELU) {
    float rv[4] = {fmaxf(ov[0], 0.f), fmaxf(ov[1], 0.f), fmaxf(ov[2], 0.f), fmaxf(ov[3], 0.f)};
    *(uint2*)(hrelu + obase) = pack4(rv);
  }
}

// ---------------- readout: sigmoid(concat(h1,h2,h3) @ Wro + bro) ------------
// h stored with permuted cols; Wro_p pre-permuted to match -> LINEAR indexing.
// Weights cached in LDS ([768][9] pad: compute reads are 2-way = conflict-free).
__global__ __launch_bounds__(256)
void readout(const unsigned short* __restrict__ h1, const unsigned short* __restrict__ h2,
             const unsigned short* __restrict__ h3, const float* __restrict__ Wro_p,
             const float* __restrict__ bro, float* __restrict__ out) {
  __shared__ float sW[768][9];
  const int t = threadIdx.x;
  for (int i = t; i < 6144; i += 256) sW[i >> 3][i & 7] = Wro_p[i];
  __syncthreads();

  int row = blockIdx.x * 4 + (t >> 6);
  int lane = t & 63;
  if (row >= NNODES) return;
  float acc[8];
#pragma unroll
  for (int t2 = 0; t2 < 8; t2++) acc[t2] = 0.f;
  const unsigned short* hs[3] = {h1 + (size_t)row * HF, h2 + (size_t)row * HF,
                                 h3 + (size_t)row * HF};
#pragma unroll
  for (int part = 0; part < 3; ++part) {
    const unsigned short* hp = hs[part];
#pragma unroll
    for (int kk = 0; kk < HF; kk += 64) {
      int q = kk + lane;
      float x = bf2f(hp[q]);
      const float* w = sW[part * 256 + q];
#pragma unroll
      for (int t2 = 0; t2 < 8; t2++) acc[t2] = fmaf(x, w[t2], acc[t2]);
    }
  }
#pragma unroll
  for (int t2 = 0; t2 < 8; t2++)
#pragma unroll
    for (int off = 32; off; off >>= 1) acc[t2] += __shfl_xor(acc[t2], off);
  if (lane == 0) {
#pragma unroll
    for (int t2 = 0; t2 < 8; t2++) {
      float v = acc[t2] + bro[t2];
      out[(size_t)row * 8 + t2] = 1.f / (1.f + expf(-v));
    }
  }
}

extern "C" void kernel_launch(void* const* d_in, const int* in_sizes, int n_in,
                              void* d_out, int out_size, void* d_ws, size_t ws_size,
                              hipStream_t stream) {
  const float* hv   = (const float*)d_in[0];
  const int*   src  = (const int*)d_in[1];
  const int*   dst  = (const int*)d_in[2];
  const float* W_in = (const float*)d_in[3];
  const float* b_in = (const float*)d_in[4];
  const float* W_ro = (const float*)d_in[5];
  const float* b_ro = (const float*)d_in[6];
  const float* fc[3]   = {(const float*)d_in[7],  (const float*)d_in[11], (const float*)d_in[15]};
  const float* al[3]   = {(const float*)d_in[8],  (const float*)d_in[12], (const float*)d_in[16]};
  const float* ar[3]   = {(const float*)d_in[9],  (const float*)d_in[13], (const float*)d_in[17]};
  const float* bias[3] = {(const float*)d_in[10], (const float*)d_in[14], (const float*)d_in[18]};
  float* out = (float*)d_out;

  const size_t NH = (size_t)NNODES * HF;   // 12.8M elems
  unsigned short* h1    = (unsigned short*)d_ws;
  unsigned short* h2    = h1 + NH;
  unsigned short* h3    = h2 + NH;
  unsigned char*  feat8 = (unsigned char*)(h3 + NH);   // NH bytes (fp8)
  unsigned short* hrelu = (unsigned short*)(feat8 + NH);   // +APAD over-read
  unsigned short* hvbf  = hrelu + NH + APAD;               // +APAD over-read
  float* el   = (float*)(hvbf + NH + APAD);
  float* er   = el + NNODES;
  int* rowptr = (int*)(er + NNODES);          // NNODES+1
  int* woff   = rowptr + NNODES + 1;          // NNODES
  int* cnt    = woff + NNODES;                // NNODES
  int* bsum   = cnt + NNODES;                 // 256
  int* boff   = bsum + 256;                   // 256
  int* col    = boff + 256;                   // NEDGES
  unsigned short* WT = (unsigned short*)(col + NEDGES);  // 4*65536 bf16
  float* Wro_p = (float*)(WT + 4 * 65536);    // 6144 floats

  const int gemm_grid = (NNODES + 63) / 64;     // 782, BM=64, all cols
  const int rd_grid = (NNODES + 3) / 4;
  const int ep_grid = (NEDGES + 255) / 256;
  const int gat_grid = (NNODES + 3) / 4;

  // ---- one-time converts ----
  conv_hv<<<(int)(NH / 2048), 256, 0, stream>>>(hv, hvbf);
  conv_wt<<<dim3(256, 4), 256, 0, stream>>>(W_in, fc[0], fc[1], fc[2], WT);
  conv_wro<<<24, 256, 0, stream>>>(W_ro, Wro_p);

  // ---- build CSR (dst-sorted adjacency), reused by all 3 layers ----
  hipMemsetAsync(cnt, 0, NNODES * sizeof(int), stream);
  hist_dst<<<ep_grid, 256, 0, stream>>>(dst, cnt);
  block_sums<<<NB, 256, 0, stream>>>(cnt, bsum);
  scan_bsums<<<1, 256, 0, stream>>>(bsum, boff);
  write_rowptr<<<NB, 256, 0, stream>>>(cnt, boff, rowptr, woff);
  scatter_csr<<<ep_grid, 256, 0, stream>>>(src, dst, woff, col);

  // hrelu = relu(hv @ W_in + b_in)   (bf16, permuted cols)
  gemm_bf16<true, false><<<gemm_grid, 256, 0, stream>>>(
      hvbf, WT, b_in, nullptr, nullptr, hrelu, nullptr, nullptr, NNODES);

  unsigned short* houts[3] = {h1, h2, h3};
  for (int l = 0; l < 3; ++l) {
    unsigned short* hl = houts[l];
    // feat8 = fp8(relu(h_prev) @ fc_l), fused exact el/er dots
    gemm_bf16<false, true><<<gemm_grid, 256, 0, stream>>>(
        hrelu, WT + (size_t)(l + 1) * 65536, nullptr, al[l], ar[l], feat8, el, er, NNODES);
    if (l < 2)
      gat_csr<true><<<gat_grid, 256, 0, stream>>>(rowptr, col, el, er, feat8, bias[l], hl, hrelu);
    else
      gat_csr<false><<<gat_grid, 256, 0, stream>>>(rowptr, col, el, er, feat8, bias[l], hl, hrelu);
  }

  readout<<<rd_grid, 256, 0, stream>>>(h1, h2, h3, Wro_p, b_ro, out);
}

// Round 11
// 349.179 us; speedup vs baseline: 1.3177x; 1.1009x over previous
//
#include <hip/hip_runtime.h>
#include <hip/hip_bf16.h>
#include <math.h>

#define NNODES 50000
#define NEDGES 800000
#define HF 256
#define NEG_SLOPE 0.2f
#define NB 196        // ceil(NNODES/256)
#define APAD 12288    // 48 pad rows * 256 for async over-read

typedef short bf16x8 __attribute__((ext_vector_type(8)));
typedef float f32x4 __attribute__((ext_vector_type(4)));
typedef float f32x2 __attribute__((ext_vector_type(2)));

__device__ __forceinline__ unsigned short f2bf(float f) {
  unsigned u = __float_as_uint(f);
  unsigned r = u + 0x7FFFu + ((u >> 16) & 1u);
  return (unsigned short)(r >> 16);
}
__device__ __forceinline__ float bf2f(unsigned short u) {
  return __uint_as_float((unsigned)u << 16);
}
__device__ __forceinline__ uint2 pack4(const float* v) {
  uint2 r;
  r.x = (unsigned)f2bf(v[0]) | ((unsigned)f2bf(v[1]) << 16);
  r.y = (unsigned)f2bf(v[2]) | ((unsigned)f2bf(v[3]) << 16);
  return r;
}
__device__ __forceinline__ uint4 pack8(const float* v) {
  uint4 r;
  r.x = (unsigned)f2bf(v[0]) | ((unsigned)f2bf(v[1]) << 16);
  r.y = (unsigned)f2bf(v[2]) | ((unsigned)f2bf(v[3]) << 16);
  r.z = (unsigned)f2bf(v[4]) | ((unsigned)f2bf(v[5]) << 16);
  r.w = (unsigned)f2bf(v[6]) | ((unsigned)f2bf(v[7]) << 16);
  return r;
}

// storage-position -> true column (within-row permutation, blocks of 64):
// p = fr*4 + j + 64*w  <->  c = j*16 + fr + 64*w
__device__ __forceinline__ int permc(int p) {
  return (p & 192) | ((p & 3) << 4) | ((p & 63) >> 2);
}

// async 16B global->LDS (wave-uniform LDS base + lane*16)
#define GLOAD_LDS16(gsrc, ldst)                                                \
  __builtin_amdgcn_global_load_lds(                                           \
      (const __attribute__((address_space(1))) unsigned int*)(const void*)(gsrc), \
      (__attribute__((address_space(3))) unsigned int*)(void*)(ldst), 16, 0, 0)

// inverse of slot = (row*4 + kb) ^ (row&7)  [16B granules of a Rx(32 bf16) tile]
__device__ __forceinline__ void slot_decode(int s, int& row, int& kb) {
  row = ((s >> 3) << 1) | (((s >> 2) & 1) ^ ((s >> 4) & 1));
  kb  = ((s & 1) ^ (row & 1)) | ((((s >> 1) & 1) ^ ((s >> 3) & 1)) << 1);
}

// ---------------- hv fp32 -> bf16 (once; raw feature order) -----------------
__global__ __launch_bounds__(256)
void conv_hv(const float* __restrict__ x, unsigned short* __restrict__ o) {
  size_t i = (size_t)(blockIdx.x * 256 + threadIdx.x) * 8;
  float4 a = *(const float4*)(x + i);
  float4 b = *(const float4*)(x + i + 4);
  float v[8] = {a.x, a.y, a.z, a.w, b.x, b.y, b.z, b.w};
  *(uint4*)(o + i) = pack8(v);
}

// ---------------- W^T bf16 pre-convert ---------------------------------------
// mat 0 (W_in): WT[n][k] = W[k][n] (A = raw hv).
// mats 1-3 (fc): WT[n][p] = W[permc(p)][n] (A = permuted hrelu).
__global__ __launch_bounds__(256)
void conv_wt(const float* __restrict__ W0, const float* __restrict__ W1,
             const float* __restrict__ W2, const float* __restrict__ W3,
             unsigned short* __restrict__ WT) {
  int mat = blockIdx.y;
  const float* W = mat == 0 ? W0 : (mat == 1 ? W1 : (mat == 2 ? W2 : W3));
  int i = blockIdx.x * 256 + threadIdx.x;
  int n = i >> 8, p = i & 255;
  int k = (mat == 0) ? p : permc(p);
  WT[(size_t)mat * 65536 + i] = f2bf(W[(size_t)k * 256 + n]);
}

// ---------------- WroT bf16 (once): [16][768], n-major, permuted k ----------
// WroT[n][kk] = bf16(Wro[(part*256 + permc(q))*8 + n]) for n<8, else 0;
// kk = part*256 + q. B-operand of the readout MFMA.
__global__ __launch_bounds__(256)
void conv_wro(const float* __restrict__ Wro, unsigned short* __restrict__ WroT) {
  int i = blockIdx.x * 256 + threadIdx.x;   // 0..12287
  if (i >= 16 * 768) return;
  int n = i / 768, kk = i % 768;
  int part = kk >> 8, q = kk & 255;
  float v = (n < 8) ? Wro[(size_t)((part << 8) + permc(q)) * 8 + n] : 0.f;
  WroT[i] = f2bf(v);
}

// ---------------- bf16 MFMA GEMM, BM=64 BN=256 BK=32, async dbuf ------------
// BIAS_RELU variant: C = bf16 hrelu (permuted cols), +bias +relu.
// DOTS variant:      C = fp8-e4m3 feat (permuted cols), + fused el/er dots.
template<bool BIAS_RELU, bool DOTS>
__global__ __launch_bounds__(256)
void gemm_bf16(const unsigned short* __restrict__ A, const unsigned short* __restrict__ WT,
               const float* __restrict__ bias,
               const float* __restrict__ al, const float* __restrict__ ar,
               void* __restrict__ Cv,
               float* __restrict__ el, float* __restrict__ er, int M) {
  __shared__ unsigned short As[2][64 * 32];    // 8 KB
  __shared__ unsigned short Bs[2][256 * 32];   // 32 KB
  __shared__ float sEl[64][4], sEr[64][4];     // 2 KB (DOTS combine)
  const int t = threadIdx.x;
  const int lane = t & 63;
  const int w = t >> 6;               // 0..3
  const int wc = w * 64;              // col quarter
  const int brow = blockIdx.x * 64;

  f32x4 acc[4][4];
#pragma unroll
  for (int i = 0; i < 4; i++)
#pragma unroll
    for (int j = 0; j < 4; j++) acc[i][j] = (f32x4)(0.f);

  // staging: A 256 granules (wave w: slots w*64+lane); B 1024 (4 per lane)
  int rA, kA;
  slot_decode(w * 64 + lane, rA, kA);
  const unsigned short* aP = A + (size_t)(brow + rA) * 256 + kA * 8;
  const unsigned short* bP[4];
#pragma unroll
  for (int i = 0; i < 4; i++) {
    int rB, kB;
    slot_decode(w * 256 + i * 64 + lane, rB, kB);
    bP[i] = WT + (size_t)rB * 256 + kB * 8;
  }
  unsigned short* lA[2] = {&As[0][w * 512], &As[1][w * 512]};
  unsigned short* lB[2] = {&Bs[0][w * 2048], &Bs[1][w * 2048]};

#define STAGE(buf, kt)                                                         \
  do {                                                                         \
    GLOAD_LDS16(aP + (kt) * 32, lA[buf]);                                      \
    GLOAD_LDS16(bP[0] + (kt) * 32, lB[buf]);                                   \
    GLOAD_LDS16(bP[1] + (kt) * 32, lB[buf] + 512);                             \
    GLOAD_LDS16(bP[2] + (kt) * 32, lB[buf] + 1024);                            \
    GLOAD_LDS16(bP[3] + (kt) * 32, lB[buf] + 1536);                            \
  } while (0)

  // fragment read offsets (swizzled byte offsets within one buffer)
  const int fr = lane & 15, fq = lane >> 4;
  int ard[4], brd[4];
#pragma unroll
  for (int i = 0; i < 4; i++) {
    int rowA = i * 16 + fr;
    ard[i] = ((rowA * 64 + fq * 16) ^ ((rowA & 7) << 4));
    int rowB = wc + i * 16 + fr;
    brd[i] = ((rowB * 64 + fq * 16) ^ ((rowB & 7) << 4));
  }

  STAGE(0, 0);
  __syncthreads();   // vmcnt(0) drain + barrier: buf0 ready
  int cur = 0;
#pragma unroll
  for (int kt = 0; kt < 8; kt++) {
    if (kt < 7) STAGE(cur ^ 1, kt + 1);   // next tile hides under MFMA
    bf16x8 af[4], bfr[4];
#pragma unroll
    for (int i = 0; i < 4; i++) {
      af[i]  = *(const bf16x8*)((const char*)As[cur] + ard[i]);
      bfr[i] = *(const bf16x8*)((const char*)Bs[cur] + brd[i]);
    }
#pragma unroll
    for (int i = 0; i < 4; i++)
#pragma unroll
      for (int j = 0; j < 4; j++)
        acc[i][j] = __builtin_amdgcn_mfma_f32_16x16x32_bf16(af[i], bfr[j], acc[i][j], 0, 0, 0);
    if (kt < 7) {
      __syncthreads();
      cur ^= 1;
    }
  }
#undef STAGE

  // epilogue: D row = (lane>>4)*4 + reg, col = wc + j*16 + fr.
  // Store positions p = wc + fr*4 + j (permuted layout): j-values contiguous.
#pragma unroll
  for (int i = 0; i < 4; i++) {
#pragma unroll
    for (int r = 0; r < 4; r++) {
      int row = brow + i * 16 + fq * 4 + r;
      if (row < M) {
        float v[4];
#pragma unroll
        for (int j = 0; j < 4; j++) {
          float x = acc[i][j][r];
          if (BIAS_RELU) x = fmaxf(x + bias[wc + j * 16 + fr], 0.f);
          v[j] = x;
        }
        if constexpr (DOTS) {   // fp8 e4m3 out (4 bytes)
          int pk = __builtin_amdgcn_cvt_pk_fp8_f32(v[0], v[1], 0, false);
          pk = __builtin_amdgcn_cvt_pk_fp8_f32(v[2], v[3], pk, true);
          *(unsigned*)((unsigned char*)Cv + (size_t)row * 256 + wc + fr * 4) = (unsigned)pk;
        } else {                // bf16 out (8 bytes)
          *(uint2*)((unsigned short*)Cv + (size_t)row * 256 + wc + fr * 4) = pack4(v);
        }
      }
    }
  }

  if constexpr (DOTS) {
    // el/er from fp32 acc (exact): j-sum -> fr-lane reduce -> LDS combine.
    float alv[4], arv[4];
#pragma unroll
    for (int j = 0; j < 4; j++) {
      int colj = wc + j * 16 + fr;
      alv[j] = al[colj];
      arv[j] = ar[colj];
    }
    float pel[16], per_[16];
#pragma unroll
    for (int i = 0; i < 4; i++)
#pragma unroll
      for (int r = 0; r < 4; r++) {
        float se = 0.f, sr = 0.f;
#pragma unroll
        for (int j = 0; j < 4; j++) {
          se = fmaf(acc[i][j][r], alv[j], se);
          sr = fmaf(acc[i][j][r], arv[j], sr);
        }
        pel[i * 4 + r] = se;
        per_[i * 4 + r] = sr;
      }
#pragma unroll
    for (int off = 1; off < 16; off <<= 1)
#pragma unroll
      for (int k = 0; k < 16; k++) {
        pel[k] += __shfl_xor(pel[k], off);
        per_[k] += __shfl_xor(per_[k], off);
      }
    if (fr == 0) {
#pragma unroll
      for (int i = 0; i < 4; i++)
#pragma unroll
        for (int r = 0; r < 4; r++) {
          int rl = i * 16 + fq * 4 + r;
          sEl[rl][w] = pel[i * 4 + r];
          sEr[rl][w] = per_[i * 4 + r];
        }
    }
    __syncthreads();
    if (t < 64) {
      int row = brow + t;
      if (row < M) {
        el[row] = sEl[t][0] + sEl[t][1] + sEl[t][2] + sEl[t][3];
        er[row] = sEr[t][0] + sEr[t][1] + sEr[t][2] + sEr[t][3];
      }
    }
  }
}

// ---------------- CSR build -------------------------------------------------
__global__ __launch_bounds__(256)
void hist_dst(const int* __restrict__ dst, int* __restrict__ cnt) {
  int e = blockIdx.x * 256 + threadIdx.x;
  if (e < NEDGES) atomicAdd(&cnt[dst[e]], 1);
}

__global__ __launch_bounds__(256)
void block_sums(const int* __restrict__ cnt, int* __restrict__ bsum) {
  __shared__ int sm[256];
  int t = threadIdx.x;
  int i = blockIdx.x * 256 + t;
  sm[t] = (i < NNODES) ? cnt[i] : 0;
  __syncthreads();
  for (int off = 128; off; off >>= 1) {
    if (t < off) sm[t] += sm[t + off];
    __syncthreads();
  }
  if (t == 0) bsum[blockIdx.x] = sm[0];
}

__global__ __launch_bounds__(256)
void scan_bsums(const int* __restrict__ bsum, int* __restrict__ boff) {
  __shared__ int sm[256];
  int t = threadIdx.x;
  sm[t] = (t < NB) ? bsum[t] : 0;
  __syncthreads();
  for (int off = 1; off < 256; off <<= 1) {
    int v = (t >= off) ? sm[t - off] : 0;
    __syncthreads();
    sm[t] += v;
    __syncthreads();
  }
  if (t < NB) boff[t] = (t == 0) ? 0 : sm[t - 1];
}

__global__ __launch_bounds__(256)
void write_rowptr(const int* __restrict__ cnt, const int* __restrict__ boff,
                  int* __restrict__ rowptr, int* __restrict__ woff) {
  __shared__ int sm[256];
  int t = threadIdx.x;
  int i = blockIdx.x * 256 + t;
  int v = (i < NNODES) ? cnt[i] : 0;
  sm[t] = v;
  __syncthreads();
  for (int off = 1; off < 256; off <<= 1) {
    int x = (t >= off) ? sm[t - off] : 0;
    __syncthreads();
    sm[t] += x;
    __syncthreads();
  }
  int excl = boff[blockIdx.x] + sm[t] - v;
  if (i < NNODES) { rowptr[i] = excl; woff[i] = excl; }
  if (i == NNODES - 1) rowptr[NNODES] = excl + v;
}

__global__ __launch_bounds__(256)
void scatter_csr(const int* __restrict__ src, const int* __restrict__ dst,
                 int* __restrict__ woff, int* __restrict__ col) {
  int e = blockIdx.x * 256 + threadIdx.x;
  if (e >= NEDGES) return;
  int d = dst[e];
  int p = atomicAdd(&woff[d], 1);
  col[p] = src[e];
}

// ---------------- fused GAT edge phase: fp8 gather, whole-wave row ----------
// One wave per dst; lane owns 4 permuted positions (4 B fp8 per edge).
// Edge (s, ex) broadcast via readlane; HW fp8->f32 converts; packed fma.
template<bool WRITE_RELU>
__global__ __launch_bounds__(256)
void gat_csr(const int* __restrict__ rowptr, const int* __restrict__ col,
             const float* __restrict__ el, const float* __restrict__ er,
             const unsigned char* __restrict__ feat8, const float* __restrict__ bias,
             unsigned short* __restrict__ h, unsigned short* __restrict__ hrelu) {
  int d = blockIdx.x * 4 + (threadIdx.x >> 6);
  int lane = threadIdx.x & 63;
  if (d >= NNODES) return;
  const int start = rowptr[d], end = rowptr[d + 1];
  // permuted bias: position p = 4*lane+m -> col (lane>>4)*64 + m*16 + (lane&15)
  float bv[4];
#pragma unroll
  for (int m = 0; m < 4; m++)
    bv[m] = bias[((lane >> 4) << 6) | (m << 4) | (lane & 15)];
  const size_t obase = (size_t)d * HF + lane * 4;
  if (start == end) {
    *(uint2*)(h + obase) = pack4(bv);
    if (WRITE_RELU) {
      float rv[4] = {fmaxf(bv[0], 0.f), fmaxf(bv[1], 0.f), fmaxf(bv[2], 0.f), fmaxf(bv[3], 0.f)};
      *(uint2*)(hrelu + obase) = pack4(rv);
    }
    return;
  }
  const float erd = er[d];

  float sm = 0.f;
  f32x2 acl = (f32x2)(0.f), ach = (f32x2)(0.f);

  for (int c0 = start; c0 < end; c0 += 64) {
    int j = c0 + lane;
    float ex = 0.f;
    int s = 0;
    if (j < end) {
      s = col[j];
      float x = el[s] + erd;
      x = x > 0.f ? x : NEG_SLOPE * x;
      ex = __expf(x);
    }
    sm += ex;
    int n = min(64, end - c0);
    for (int q = 0; q < n; q += 8) {
      int su[8];
      float eu[8];
#pragma unroll
      for (int u = 0; u < 8; u++) {
        su[u] = __builtin_amdgcn_readlane(s, q + u);
        eu[u] = __uint_as_float(
            (unsigned)__builtin_amdgcn_readlane((int)__float_as_uint(ex), q + u));
      }
      unsigned fv[8];
#pragma unroll
      for (int u = 0; u < 8; u++)
        fv[u] = *(const unsigned*)(feat8 + (size_t)su[u] * 256 + lane * 4);
#pragma unroll
      for (int u = 0; u < 8; u++) {
        f32x2 lo = __builtin_amdgcn_cvt_pk_f32_fp8((int)fv[u], false);
        f32x2 hi = __builtin_amdgcn_cvt_pk_f32_fp8((int)fv[u], true);
        f32x2 ev = {eu[u], eu[u]};
        acl = lo * ev + acl;
        ach = hi * ev + ach;
      }
    }
  }
#pragma unroll
  for (int off = 32; off; off >>= 1) sm += __shfl_xor(sm, off);

  const float rcp = 1.f / sm;
  float ov[4];
  ov[0] = fmaf(acl.x, rcp, bv[0]);
  ov[1] = fmaf(acl.y, rcp, bv[1]);
  ov[2] = fmaf(ach.x, rcp, bv[2]);
  ov[3] = fmaf(ach.y, rcp, bv[3]);
  *(uint2*)(h + obase) = pack4(ov);
  if (WRITE_RELU) {
    float rv[4] = {fmaxf(ov[0], 0.f), fmaxf(ov[1], 0.f), fmaxf(ov[2], 0.f), fmaxf(ov[3], 0.f)};
    *(uint2*)(hrelu + obase) = pack4(rv);
  }
}

// ---------------- readout: MFMA GEMM [N x 768] @ WroT^T -> sigmoid ----------
// One wave per 16 rows; acc = one 16x16 tile (cols 0..7 used). A-fragments
// 16B/lane direct from global h (permuted layout matches WroT's permuted k);
// B-fragments 16B/lane from WroT (24 KB, L1-resident). No LDS, no barriers.
__global__ __launch_bounds__(256)
void readout(const unsigned short* __restrict__ h1, const unsigned short* __restrict__ h2,
             const unsigned short* __restrict__ h3, const unsigned short* __restrict__ WroT,
             const float* __restrict__ bro, float* __restrict__ out) {
  const int t = threadIdx.x;
  const int lane = t & 63;
  const int w = t >> 6;
  const int fr = lane & 15, fq = lane >> 4;
  const int r0 = blockIdx.x * 64 + w * 16;   // wave's first row
  if (r0 >= NNODES) return;                  // whole-wave guard (50000=782*64-48)
  const unsigned short* hs[3] = {h1, h2, h3};

  f32x4 acc = (f32x4)(0.f);
  const int koff = fq * 8;
#pragma unroll
  for (int part = 0; part < 3; ++part) {
    const unsigned short* hp = hs[part] + (size_t)(r0 + fr) * HF + koff;
    const unsigned short* wp = WroT + fr * 768 + part * 256 + koff;
#pragma unroll
    for (int kb = 0; kb < 8; ++kb) {
      bf16x8 af = *(const bf16x8*)(hp + kb * 32);
      bf16x8 bf = *(const bf16x8*)(wp + kb * 32);
      acc = __builtin_amdgcn_mfma_f32_16x16x32_bf16(af, bf, acc, 0, 0, 0);
    }
  }
  // C: row = fq*4 + reg, col = fr (only cols 0..7 are real outputs)
  if (fr < 8) {
    const float b = bro[fr];
#pragma unroll
    for (int r = 0; r < 4; ++r) {
      int row = r0 + fq * 4 + r;
      float v = acc[r] + b;
      out[(size_t)row * 8 + fr] = 1.f / (1.f + expf(-v));
    }
  }
}

extern "C" void kernel_launch(void* const* d_in, const int* in_sizes, int n_in,
                              void* d_out, int out_size, void* d_ws, size_t ws_size,
                              hipStream_t stream) {
  const float* hv   = (const float*)d_in[0];
  const int*   src  = (const int*)d_in[1];
  const int*   dst  = (const int*)d_in[2];
  const float* W_in = (const float*)d_in[3];
  const float* b_in = (const float*)d_in[4];
  const float* W_ro = (const float*)d_in[5];
  const float* b_ro = (const float*)d_in[6];
  const float* fc[3]   = {(const float*)d_in[7],  (const float*)d_in[11], (const float*)d_in[15]};
  const float* al[3]   = {(const float*)d_in[8],  (const float*)d_in[12], (const float*)d_in[16]};
  const float* ar[3]   = {(const float*)d_in[9],  (const float*)d_in[13], (const float*)d_in[17]};
  const float* bias[3] = {(const float*)d_in[10], (const float*)d_in[14], (const float*)d_in[18]};
  float* out = (float*)d_out;

  const size_t NH = (size_t)NNODES * HF;   // 12.8M elems
  unsigned short* h1    = (unsigned short*)d_ws;
  unsigned short* h2    = h1 + NH;
  unsigned short* h3    = h2 + NH;
  unsigned char*  feat8 = (unsigned char*)(h3 + NH);   // NH bytes (fp8)
  unsigned short* hrelu = (unsigned short*)(feat8 + NH);   // +APAD over-read
  unsigned short* hvbf  = hrelu + NH + APAD;               // +APAD over-read
  float* el   = (float*)(hvbf + NH + APAD);
  float* er   = el + NNODES;
  int* rowptr = (int*)(er + NNODES);          // NNODES+1
  int* woff   = rowptr + NNODES + 1;          // NNODES
  int* cnt    = woff + NNODES;                // NNODES
  int* bsum   = cnt + NNODES;                 // 256
  int* boff   = bsum + 256;                   // 256
  int* col    = boff + 256;                   // NEDGES
  unsigned short* WT = (unsigned short*)(col + NEDGES);  // 4*65536 bf16
  unsigned short* WroT = WT + 4 * 65536;      // 16*768 bf16

  const int gemm_grid = (NNODES + 63) / 64;     // 782, BM=64, all cols
  const int ep_grid = (NEDGES + 255) / 256;
  const int gat_grid = (NNODES + 3) / 4;
  const int ro_grid = (NNODES + 63) / 64;       // 782, 64 rows/block

  // ---- one-time converts ----
  conv_hv<<<(int)(NH / 2048), 256, 0, stream>>>(hv, hvbf);
  conv_wt<<<dim3(256, 4), 256, 0, stream>>>(W_in, fc[0], fc[1], fc[2], WT);
  conv_wro<<<48, 256, 0, stream>>>(W_ro, WroT);

  // ---- build CSR (dst-sorted adjacency), reused by all 3 layers ----
  hipMemsetAsync(cnt, 0, NNODES * sizeof(int), stream);
  hist_dst<<<ep_grid, 256, 0, stream>>>(dst, cnt);
  block_sums<<<NB, 256, 0, stream>>>(cnt, bsum);
  scan_bsums<<<1, 256, 0, stream>>>(bsum, boff);
  write_rowptr<<<NB, 256, 0, stream>>>(cnt, boff, rowptr, woff);
  scatter_csr<<<ep_grid, 256, 0, stream>>>(src, dst, woff, col);

  // hrelu = relu(hv @ W_in + b_in)   (bf16, permuted cols)
  gemm_bf16<true, false><<<gemm_grid, 256, 0, stream>>>(
      hvbf, WT, b_in, nullptr, nullptr, hrelu, nullptr, nullptr, NNODES);

  unsigned short* houts[3] = {h1, h2, h3};
  for (int l = 0; l < 3; ++l) {
    unsigned short* hl = houts[l];
    // feat8 = fp8(relu(h_prev) @ fc_l), fused exact el/er dots
    gemm_bf16<false, true><<<gemm_grid, 256, 0, stream>>>(
        hrelu, WT + (size_t)(l + 1) * 65536, nullptr, al[l], ar[l], feat8, el, er, NNODES);
    if (l < 2)
      gat_csr<true><<<gat_grid, 256, 0, stream>>>(rowptr, col, el, er, feat8, bias[l], hl, hrelu);
    else
      gat_csr<false><<<gat_grid, 256, 0, stream>>>(rowptr, col, el, er, feat8, bias[l], hl, hrelu);
  }

  readout<<<ro_grid, 256, 0, stream>>>(h1, h2, h3, WroT, b_ro, out);
}

// Round 12
// 279.570 us; speedup vs baseline: 1.6458x; 1.2490x over previous
//
#include <hip/hip_runtime.h>
#include <hip/hip_bf16.h>
#include <math.h>

#define NNODES 50000
#define NEDGES 800000
#define HF 256
#define NEG_SLOPE 0.2f
#define APAD 12288    // 48 pad rows * 256 for async over-read
#define CHUNK 3125    // NEDGES / 256 sort blocks
#define NBUCK 196     // ceil(NNODES/256) coarse buckets (dst>>8)
#define NG (NBUCK * 256)   // 50176 (bucket, block) counters

typedef short bf16x8 __attribute__((ext_vector_type(8)));
typedef float f32x4 __attribute__((ext_vector_type(4)));
typedef float f32x2 __attribute__((ext_vector_type(2)));

__device__ __forceinline__ unsigned short f2bf(float f) {
  unsigned u = __float_as_uint(f);
  unsigned r = u + 0x7FFFu + ((u >> 16) & 1u);
  return (unsigned short)(r >> 16);
}
__device__ __forceinline__ float bf2f(unsigned short u) {
  return __uint_as_float((unsigned)u << 16);
}
__device__ __forceinline__ uint2 pack4(const float* v) {
  uint2 r;
  r.x = (unsigned)f2bf(v[0]) | ((unsigned)f2bf(v[1]) << 16);
  r.y = (unsigned)f2bf(v[2]) | ((unsigned)f2bf(v[3]) << 16);
  return r;
}
__device__ __forceinline__ uint4 pack8(const float* v) {
  uint4 r;
  r.x = (unsigned)f2bf(v[0]) | ((unsigned)f2bf(v[1]) << 16);
  r.y = (unsigned)f2bf(v[2]) | ((unsigned)f2bf(v[3]) << 16);
  r.z = (unsigned)f2bf(v[4]) | ((unsigned)f2bf(v[5]) << 16);
  r.w = (unsigned)f2bf(v[6]) | ((unsigned)f2bf(v[7]) << 16);
  return r;
}

// storage-position -> true column (within-row permutation, blocks of 64):
// p = fr*4 + j + 64*w  <->  c = j*16 + fr + 64*w
__device__ __forceinline__ int permc(int p) {
  return (p & 192) | ((p & 3) << 4) | ((p & 63) >> 2);
}

// async 16B global->LDS (wave-uniform LDS base + lane*16)
#define GLOAD_LDS16(gsrc, ldst)                                                \
  __builtin_amdgcn_global_load_lds(                                           \
      (const __attribute__((address_space(1))) unsigned int*)(const void*)(gsrc), \
      (__attribute__((address_space(3))) unsigned int*)(void*)(ldst), 16, 0, 0)

// inverse of slot = (row*4 + kb) ^ (row&7)  [16B granules of a Rx(32 bf16) tile]
__device__ __forceinline__ void slot_decode(int s, int& row, int& kb) {
  row = ((s >> 3) << 1) | (((s >> 2) & 1) ^ ((s >> 4) & 1));
  kb  = ((s & 1) ^ (row & 1)) | ((((s >> 1) & 1) ^ ((s >> 3) & 1)) << 1);
}

// ---------------- hv fp32 -> bf16 (once; raw feature order) -----------------
__global__ __launch_bounds__(256)
void conv_hv(const float* __restrict__ x, unsigned short* __restrict__ o) {
  size_t i = (size_t)(blockIdx.x * 256 + threadIdx.x) * 8;
  float4 a = *(const float4*)(x + i);
  float4 b = *(const float4*)(x + i + 4);
  float v[8] = {a.x, a.y, a.z, a.w, b.x, b.y, b.z, b.w};
  *(uint4*)(o + i) = pack8(v);
}

// ---------------- W^T bf16 pre-convert ---------------------------------------
__global__ __launch_bounds__(256)
void conv_wt(const float* __restrict__ W0, const float* __restrict__ W1,
             const float* __restrict__ W2, const float* __restrict__ W3,
             unsigned short* __restrict__ WT) {
  int mat = blockIdx.y;
  const float* W = mat == 0 ? W0 : (mat == 1 ? W1 : (mat == 2 ? W2 : W3));
  int i = blockIdx.x * 256 + threadIdx.x;
  int n = i >> 8, p = i & 255;
  int k = (mat == 0) ? p : permc(p);
  WT[(size_t)mat * 65536 + i] = f2bf(W[(size_t)k * 256 + n]);
}

// ---------------- WroT bf16 (once): [16][768], n-major, permuted k ----------
__global__ __launch_bounds__(256)
void conv_wro(const float* __restrict__ Wro, unsigned short* __restrict__ WroT) {
  int i = blockIdx.x * 256 + threadIdx.x;   // 0..12287
  if (i >= 16 * 768) return;
  int n = i / 768, kk = i % 768;
  int part = kk >> 8, q = kk & 255;
  float v = (n < 8) ? Wro[(size_t)((part << 8) + permc(q)) * 8 + n] : 0.f;
  WroT[i] = f2bf(v);
}

// ---------------- bf16 MFMA GEMM, BM=64 BN=256 BK=32, async dbuf ------------
template<bool BIAS_RELU, bool DOTS>
__global__ __launch_bounds__(256)
void gemm_bf16(const unsigned short* __restrict__ A, const unsigned short* __restrict__ WT,
               const float* __restrict__ bias,
               const float* __restrict__ al, const float* __restrict__ ar,
               void* __restrict__ Cv,
               float* __restrict__ el, float* __restrict__ er, int M) {
  __shared__ unsigned short As[2][64 * 32];    // 8 KB
  __shared__ unsigned short Bs[2][256 * 32];   // 32 KB
  __shared__ float sEl[64][4], sEr[64][4];     // 2 KB (DOTS combine)
  const int t = threadIdx.x;
  const int lane = t & 63;
  const int w = t >> 6;               // 0..3
  const int wc = w * 64;              // col quarter
  const int brow = blockIdx.x * 64;

  f32x4 acc[4][4];
#pragma unroll
  for (int i = 0; i < 4; i++)
#pragma unroll
    for (int j = 0; j < 4; j++) acc[i][j] = (f32x4)(0.f);

  int rA, kA;
  slot_decode(w * 64 + lane, rA, kA);
  const unsigned short* aP = A + (size_t)(brow + rA) * 256 + kA * 8;
  const unsigned short* bP[4];
#pragma unroll
  for (int i = 0; i < 4; i++) {
    int rB, kB;
    slot_decode(w * 256 + i * 64 + lane, rB, kB);
    bP[i] = WT + (size_t)rB * 256 + kB * 8;
  }
  unsigned short* lA[2] = {&As[0][w * 512], &As[1][w * 512]};
  unsigned short* lB[2] = {&Bs[0][w * 2048], &Bs[1][w * 2048]};

#define STAGE(buf, kt)                                                         \
  do {                                                                         \
    GLOAD_LDS16(aP + (kt) * 32, lA[buf]);                                      \
    GLOAD_LDS16(bP[0] + (kt) * 32, lB[buf]);                                   \
    GLOAD_LDS16(bP[1] + (kt) * 32, lB[buf] + 512);                             \
    GLOAD_LDS16(bP[2] + (kt) * 32, lB[buf] + 1024);                            \
    GLOAD_LDS16(bP[3] + (kt) * 32, lB[buf] + 1536);                            \
  } while (0)

  const int fr = lane & 15, fq = lane >> 4;
  int ard[4], brd[4];
#pragma unroll
  for (int i = 0; i < 4; i++) {
    int rowA = i * 16 + fr;
    ard[i] = ((rowA * 64 + fq * 16) ^ ((rowA & 7) << 4));
    int rowB = wc + i * 16 + fr;
    brd[i] = ((rowB * 64 + fq * 16) ^ ((rowB & 7) << 4));
  }

  STAGE(0, 0);
  __syncthreads();   // vmcnt(0) drain + barrier: buf0 ready
  int cur = 0;
#pragma unroll
  for (int kt = 0; kt < 8; kt++) {
    if (kt < 7) STAGE(cur ^ 1, kt + 1);   // next tile hides under MFMA
    bf16x8 af[4], bfr[4];
#pragma unroll
    for (int i = 0; i < 4; i++) {
      af[i]  = *(const bf16x8*)((const char*)As[cur] + ard[i]);
      bfr[i] = *(const bf16x8*)((const char*)Bs[cur] + brd[i]);
    }
#pragma unroll
    for (int i = 0; i < 4; i++)
#pragma unroll
      for (int j = 0; j < 4; j++)
        acc[i][j] = __builtin_amdgcn_mfma_f32_16x16x32_bf16(af[i], bfr[j], acc[i][j], 0, 0, 0);
    if (kt < 7) {
      __syncthreads();
      cur ^= 1;
    }
  }
#undef STAGE

  // epilogue: D row = (lane>>4)*4 + reg, col = wc + j*16 + fr.
#pragma unroll
  for (int i = 0; i < 4; i++) {
#pragma unroll
    for (int r = 0; r < 4; r++) {
      int row = brow + i * 16 + fq * 4 + r;
      if (row < M) {
        float v[4];
#pragma unroll
        for (int j = 0; j < 4; j++) {
          float x = acc[i][j][r];
          if (BIAS_RELU) x = fmaxf(x + bias[wc + j * 16 + fr], 0.f);
          v[j] = x;
        }
        if constexpr (DOTS) {   // fp8 e4m3 out (4 bytes)
          int pk = __builtin_amdgcn_cvt_pk_fp8_f32(v[0], v[1], 0, false);
          pk = __builtin_amdgcn_cvt_pk_fp8_f32(v[2], v[3], pk, true);
          *(unsigned*)((unsigned char*)Cv + (size_t)row * 256 + wc + fr * 4) = (unsigned)pk;
        } else {                // bf16 out (8 bytes)
          *(uint2*)((unsigned short*)Cv + (size_t)row * 256 + wc + fr * 4) = pack4(v);
        }
      }
    }
  }

  if constexpr (DOTS) {
    float alv[4], arv[4];
#pragma unroll
    for (int j = 0; j < 4; j++) {
      int colj = wc + j * 16 + fr;
      alv[j] = al[colj];
      arv[j] = ar[colj];
    }
    float pel[16], per_[16];
#pragma unroll
    for (int i = 0; i < 4; i++)
#pragma unroll
      for (int r = 0; r < 4; r++) {
        float se = 0.f, sr = 0.f;
#pragma unroll
        for (int j = 0; j < 4; j++) {
          se = fmaf(acc[i][j][r], alv[j], se);
          sr = fmaf(acc[i][j][r], arv[j], sr);
        }
        pel[i * 4 + r] = se;
        per_[i * 4 + r] = sr;
      }
#pragma unroll
    for (int off = 1; off < 16; off <<= 1)
#pragma unroll
      for (int k = 0; k < 16; k++) {
        pel[k] += __shfl_xor(pel[k], off);
        per_[k] += __shfl_xor(per_[k], off);
      }
    if (fr == 0) {
#pragma unroll
      for (int i = 0; i < 4; i++)
#pragma unroll
        for (int r = 0; r < 4; r++) {
          int rl = i * 16 + fq * 4 + r;
          sEl[rl][w] = pel[i * 4 + r];
          sEr[rl][w] = per_[i * 4 + r];
        }
    }
    __syncthreads();
    if (t < 64) {
      int row = brow + t;
      if (row < M) {
        el[row] = sEl[t][0] + sEl[t][1] + sEl[t][2] + sEl[t][3];
        er[row] = sEr[t][0] + sEr[t][1] + sEr[t][2] + sEr[t][3];
      }
    }
  }
}

// ---------------- CSR build: 2-pass bucket sort, no global atomics ----------
// Pass A1: per-sort-block LDS histogram of coarse buckets (dst>>8).
__global__ __launch_bounds__(256)
void hist_coarse(const int* __restrict__ dst, int* __restrict__ gh) {
  __shared__ int lh[NBUCK];
  const int t = threadIdx.x, blk = blockIdx.x;
  if (t < NBUCK) lh[t] = 0;
  __syncthreads();
  const int base = blk * CHUNK;
  for (int i = t; i < CHUNK; i += 256)
    atomicAdd(&lh[dst[base + i] >> 8], 1);
  __syncthreads();
  if (t < NBUCK) gh[t * 256 + blk] = lh[t];   // bucket-major, then block
}

// scan of gh[NG] -> abase (exclusive prefix); 3-phase, reused machinery
__global__ __launch_bounds__(256)
void bsum2(const int* __restrict__ g, int* __restrict__ bsum) {
  __shared__ int sm[256];
  int t = threadIdx.x;
  sm[t] = g[blockIdx.x * 256 + t];
  __syncthreads();
  for (int off = 128; off; off >>= 1) {
    if (t < off) sm[t] += sm[t + off];
    __syncthreads();
  }
  if (t == 0) bsum[blockIdx.x] = sm[0];
}

__global__ __launch_bounds__(256)
void sscan2(const int* __restrict__ bsum, int* __restrict__ boff) {
  __shared__ int sm[256];
  int t = threadIdx.x;
  sm[t] = (t < NBUCK) ? bsum[t] : 0;
  __syncthreads();
  for (int o = 1; o < 256; o <<= 1) {
    int v = (t >= o) ? sm[t - o] : 0;
    __syncthreads();
    sm[t] += v;
    __syncthreads();
  }
  if (t < NBUCK) boff[t] = (t == 0) ? 0 : sm[t - 1];
}

__global__ __launch_bounds__(256)
void abase2(const int* __restrict__ g, const int* __restrict__ boff,
            int* __restrict__ abase) {
  __shared__ int sm[256];
  int t = threadIdx.x;
  int i = blockIdx.x * 256 + t;
  int v = g[i];
  sm[t] = v;
  __syncthreads();
  for (int o = 1; o < 256; o <<= 1) {
    int x = (t >= o) ? sm[t - o] : 0;
    __syncthreads();
    sm[t] += x;
    __syncthreads();
  }
  abase[i] = boff[blockIdx.x] + sm[t] - v;
}

// Pass A2: scatter (src,dst) into bucket-grouped ebuf; LDS append counters.
__global__ __launch_bounds__(256)
void scatter_coarse(const int* __restrict__ src, const int* __restrict__ dst,
                    const int* __restrict__ abase, uint2* __restrict__ ebuf) {
  __shared__ int off[NBUCK];
  const int t = threadIdx.x, blk = blockIdx.x;
  if (t < NBUCK) off[t] = abase[t * 256 + blk];
  __syncthreads();
  const int base = blk * CHUNK;
  for (int i = t; i < CHUNK; i += 256) {
    int e = base + i;
    int d = dst[e], s = src[e];
    int p = atomicAdd(&off[d >> 8], 1);   // LDS atomic
    ebuf[p] = make_uint2((unsigned)s, (unsigned)d);
  }
}

// Pass B: one block per bucket; fine 256-way sort in LDS -> rowptr + col.
__global__ __launch_bounds__(256)
void fine_sort(const uint2* __restrict__ ebuf, const int* __restrict__ abase,
               int* __restrict__ rowptr, int* __restrict__ col) {
  __shared__ int hist[256], pre[256], off[256];
  const int t = threadIdx.x, b = blockIdx.x;
  const int bstart = abase[b * 256];
  const int bend = (b < NBUCK - 1) ? abase[(b + 1) * 256] : NEDGES;
  hist[t] = 0;
  __syncthreads();
  for (int e = bstart + t; e < bend; e += 256)
    atomicAdd(&hist[ebuf[e].y & 255], 1);
  __syncthreads();
  pre[t] = hist[t];
  __syncthreads();
  for (int o = 1; o < 256; o <<= 1) {
    int v = (t >= o) ? pre[t - o] : 0;
    __syncthreads();
    pre[t] += v;
    __syncthreads();
  }
  const int excl = bstart + pre[t] - hist[t];
  const int node = b * 256 + t;
  if (node < NNODES) rowptr[node] = excl;
  if (node == NNODES - 1) rowptr[NNODES] = NEDGES;
  off[t] = excl;
  __syncthreads();
  for (int e = bstart + t; e < bend; e += 256) {
    uint2 ed = ebuf[e];
    int p = atomicAdd(&off[ed.y & 255], 1);   // LDS atomic
    col[p] = (int)ed.x;
  }
}

// ---------------- fused GAT edge phase: fp8 gather, whole-wave row ----------
template<bool WRITE_RELU>
__global__ __launch_bounds__(256)
void gat_csr(const int* __restrict__ rowptr, const int* __restrict__ col,
             const float* __restrict__ el, const float* __restrict__ er,
             const unsigned char* __restrict__ feat8, const float* __restrict__ bias,
             unsigned short* __restrict__ h, unsigned short* __restrict__ hrelu) {
  int d = blockIdx.x * 4 + (threadIdx.x >> 6);
  int lane = threadIdx.x & 63;
  if (d >= NNODES) return;
  const int start = rowptr[d], end = rowptr[d + 1];
  float bv[4];
#pragma unroll
  for (int m = 0; m < 4; m++)
    bv[m] = bias[((lane >> 4) << 6) | (m << 4) | (lane & 15)];
  const size_t obase = (size_t)d * HF + lane * 4;
  if (start == end) {
    *(uint2*)(h + obase) = pack4(bv);
    if (WRITE_RELU) {
      float rv[4] = {fmaxf(bv[0], 0.f), fmaxf(bv[1], 0.f), fmaxf(bv[2], 0.f), fmaxf(bv[3], 0.f)};
      *(uint2*)(hrelu + obase) = pack4(rv);
    }
    return;
  }
  const float erd = er[d];

  float sm = 0.f;
  f32x2 acl = (f32x2)(0.f), ach = (f32x2)(0.f);

  for (int c0 = start; c0 < end; c0 += 64) {
    int j = c0 + lane;
    float ex = 0.f;
    int s = 0;
    if (j < end) {
      s = col[j];
      float x = el[s] + erd;
      x = x > 0.f ? x : NEG_SLOPE * x;
      ex = __expf(x);
    }
    sm += ex;
    int n = min(64, end - c0);
    for (int q = 0; q < n; q += 8) {
      int su[8];
      float eu[8];
#pragma unroll
      for (int u = 0; u < 8; u++) {
        su[u] = __builtin_amdgcn_readlane(s, q + u);
        eu[u] = __uint_as_float(
            (unsigned)__builtin_amdgcn_readlane((int)__float_as_uint(ex), q + u));
      }
      unsigned fv[8];
#pragma unroll
      for (int u = 0; u < 8; u++)
        fv[u] = *(const unsigned*)(feat8 + (size_t)su[u] * 256 + lane * 4);
#pragma unroll
      for (int u = 0; u < 8; u++) {
        f32x2 lo = __builtin_amdgcn_cvt_pk_f32_fp8((int)fv[u], false);
        f32x2 hi = __builtin_amdgcn_cvt_pk_f32_fp8((int)fv[u], true);
        f32x2 ev = {eu[u], eu[u]};
        acl = lo * ev + acl;
        ach = hi * ev + ach;
      }
    }
  }
#pragma unroll
  for (int off = 32; off; off >>= 1) sm += __shfl_xor(sm, off);

  const float rcp = 1.f / sm;
  float ov[4];
  ov[0] = fmaf(acl.x, rcp, bv[0]);
  ov[1] = fmaf(acl.y, rcp, bv[1]);
  ov[2] = fmaf(ach.x, rcp, bv[2]);
  ov[3] = fmaf(ach.y, rcp, bv[3]);
  *(uint2*)(h + obase) = pack4(ov);
  if (WRITE_RELU) {
    float rv[4] = {fmaxf(ov[0], 0.f), fmaxf(ov[1], 0.f), fmaxf(ov[2], 0.f), fmaxf(ov[3], 0.f)};
    *(uint2*)(hrelu + obase) = pack4(rv);
  }
}

// ---------------- readout: MFMA GEMM [N x 768] @ WroT^T -> sigmoid ----------
__global__ __launch_bounds__(256)
void readout(const unsigned short* __restrict__ h1, const unsigned short* __restrict__ h2,
             const unsigned short* __restrict__ h3, const unsigned short* __restrict__ WroT,
             const float* __restrict__ bro, float* __restrict__ out) {
  const int t = threadIdx.x;
  const int lane = t & 63;
  const int w = t >> 6;
  const int fr = lane & 15, fq = lane >> 4;
  const int r0 = blockIdx.x * 64 + w * 16;   // wave's first row
  if (r0 >= NNODES) return;                  // whole-wave guard
  const unsigned short* hs[3] = {h1, h2, h3};

  f32x4 acc = (f32x4)(0.f);
  const int koff = fq * 8;
#pragma unroll
  for (int part = 0; part < 3; ++part) {
    const unsigned short* hp = hs[part] + (size_t)(r0 + fr) * HF + koff;
    const unsigned short* wp = WroT + fr * 768 + part * 256 + koff;
#pragma unroll
    for (int kb = 0; kb < 8; ++kb) {
      bf16x8 af = *(const bf16x8*)(hp + kb * 32);
      bf16x8 bf = *(const bf16x8*)(wp + kb * 32);
      acc = __builtin_amdgcn_mfma_f32_16x16x32_bf16(af, bf, acc, 0, 0, 0);
    }
  }
  if (fr < 8) {
    const float b = bro[fr];
#pragma unroll
    for (int r = 0; r < 4; ++r) {
      int row = r0 + fq * 4 + r;
      float v = acc[r] + b;
      out[(size_t)row * 8 + fr] = 1.f / (1.f + expf(-v));
    }
  }
}

extern "C" void kernel_launch(void* const* d_in, const int* in_sizes, int n_in,
                              void* d_out, int out_size, void* d_ws, size_t ws_size,
                              hipStream_t stream) {
  const float* hv   = (const float*)d_in[0];
  const int*   src  = (const int*)d_in[1];
  const int*   dst  = (const int*)d_in[2];
  const float* W_in = (const float*)d_in[3];
  const float* b_in = (const float*)d_in[4];
  const float* W_ro = (const float*)d_in[5];
  const float* b_ro = (const float*)d_in[6];
  const float* fc[3]   = {(const float*)d_in[7],  (const float*)d_in[11], (const float*)d_in[15]};
  const float* al[3]   = {(const float*)d_in[8],  (const float*)d_in[12], (const float*)d_in[16]};
  const float* ar[3]   = {(const float*)d_in[9],  (const float*)d_in[13], (const float*)d_in[17]};
  const float* bias[3] = {(const float*)d_in[10], (const float*)d_in[14], (const float*)d_in[18]};
  float* out = (float*)d_out;

  const size_t NH = (size_t)NNODES * HF;   // 12.8M elems
  unsigned short* h1    = (unsigned short*)d_ws;
  unsigned short* h2    = h1 + NH;
  unsigned short* h3    = h2 + NH;
  unsigned char*  feat8 = (unsigned char*)(h3 + NH);   // NH bytes (fp8)
  unsigned short* hrelu = (unsigned short*)(feat8 + NH);   // +APAD over-read
  unsigned short* hvbf  = hrelu + NH + APAD;               // +APAD over-read
  float* el   = (float*)(hvbf + NH + APAD);
  float* er   = el + NNODES;
  int* rowptr = (int*)(er + NNODES);          // NNODES+1
  int* gh     = rowptr + NNODES + 1;          // NG
  int* abase  = gh + NG;                      // NG
  int* bsum   = abase + NG;                   // 256
  int* boff   = bsum + 256;                   // 256
  int* col    = boff + 256;                   // NEDGES
  uint2* ebuf = (uint2*)(col + NEDGES);       // NEDGES uint2
  unsigned short* WT = (unsigned short*)(ebuf + NEDGES);  // 4*65536 bf16
  unsigned short* WroT = WT + 4 * 65536;      // 16*768 bf16

  const int gemm_grid = (NNODES + 63) / 64;     // 782, BM=64, all cols
  const int gat_grid = (NNODES + 3) / 4;
  const int ro_grid = (NNODES + 63) / 64;       // 782, 64 rows/block

  // ---- one-time converts ----
  conv_hv<<<(int)(NH / 2048), 256, 0, stream>>>(hv, hvbf);
  conv_wt<<<dim3(256, 4), 256, 0, stream>>>(W_in, fc[0], fc[1], fc[2], WT);
  conv_wro<<<48, 256, 0, stream>>>(W_ro, WroT);

  // ---- CSR build: 2-pass bucket sort (no global atomics) ----
  hist_coarse<<<256, 256, 0, stream>>>(dst, gh);
  bsum2<<<NBUCK, 256, 0, stream>>>(gh, bsum);
  sscan2<<<1, 256, 0, stream>>>(bsum, boff);
  abase2<<<NBUCK, 256, 0, stream>>>(gh, boff, abase);
  scatter_coarse<<<256, 256, 0, stream>>>(src, dst, abase, ebuf);
  fine_sort<<<NBUCK, 256, 0, stream>>>(ebuf, abase, rowptr, col);

  // hrelu = relu(hv @ W_in + b_in)   (bf16, permuted cols)
  gemm_bf16<true, false><<<gemm_grid, 256, 0, stream>>>(
      hvbf, WT, b_in, nullptr, nullptr, hrelu, nullptr, nullptr, NNODES);

  unsigned short* houts[3] = {h1, h2, h3};
  for (int l = 0; l < 3; ++l) {
    unsigned short* hl = houts[l];
    // feat8 = fp8(relu(h_prev) @ fc_l), fused exact el/er dots
    gemm_bf16<false, true><<<gemm_grid, 256, 0, stream>>>(
        hrelu, WT + (size_t)(l + 1) * 65536, nullptr, al[l], ar[l], feat8, el, er, NNODES);
    if (l < 2)
      gat_csr<true><<<gat_grid, 256, 0, stream>>>(rowptr, col, el, er, feat8, bias[l], hl, hrelu);
    else
      gat_csr<false><<<gat_grid, 256, 0, stream>>>(rowptr, col, el, er, feat8, bias[l], hl, hrelu);
  }

  readout<<<ro_grid, 256, 0, stream>>>(h1, h2, h3, WroT, b_ro, out);
}